// Round 2
// baseline (992.760 us; speedup 1.0000x reference)
//
#include <hip/hip_runtime.h>
#include <cstdint>
#include <cstddef>

// ---- problem dims (fixed) ----
#define B_SZ 1024
#define N_SZ 128
#define DIN 256
#define HID 256
#define DOUT 256
#define KD 512   // 4*N
#define NCHUNK 4
#define BC (B_SZ / NCHUNK)          // 256 batches per chunk
#define MC (BC * N_SZ)              // 32768 rows per chunk

typedef unsigned short u16;
typedef __bf16 bf16x8 __attribute__((ext_vector_type(8)));
typedef float floatx4 __attribute__((ext_vector_type(4)));
typedef unsigned short u16x8 __attribute__((ext_vector_type(8)));
typedef unsigned short u16x4 __attribute__((ext_vector_type(4)));

__device__ __forceinline__ u16 f2bf(float f) {
    unsigned int u = __float_as_uint(f);
    u += 0x7fffu + ((u >> 16) & 1u);   // RNE
    return (u16)(u >> 16);
}
__device__ __forceinline__ float bf2f(u16 h) {
    unsigned int u = ((unsigned int)h) << 16;
    return __uint_as_float(u);
}

__device__ __forceinline__ void gload16(const void* g, void* lds) {
    __builtin_amdgcn_global_load_lds(
        (__attribute__((address_space(1))) void*)const_cast<void*>(g),
        (__attribute__((address_space(3))) void*)lds,
        16, 0, 0);
}

// ============================================================================
// Split-precision GEMM: C = act( A·Bt^T + bias ),  A ≈ Ahi+Alo, Bt ≈ Bhi+Blo
// 3-pass MFMA: hi·hi + hi·lo + lo·hi  (~fp32 precision).
// A planes: [M][K] bf16 row-major; Bt planes: [N][K] bf16 row-major.
// OUT_MODE: 0 = fp32 single, 1 = bf16 single, 2 = bf16 hi/lo planes.
// ============================================================================
template<int DO_RELU, int OUT_MODE>
__global__ __launch_bounds__(256)
void gemm3(const u16* __restrict__ Ahi, const u16* __restrict__ Alo,
           const u16* __restrict__ Bhi, const u16* __restrict__ Blo,
           const float* __restrict__ bias,
           void* __restrict__ C0, u16* __restrict__ Clo,
           int M, int N, int K)
{
    __shared__ u16 Ash[128 * 64];
    __shared__ u16 Asl[128 * 64];
    __shared__ u16 Bsh[128 * 64];
    __shared__ u16 Bsl[128 * 64];
    const int tid  = threadIdx.x;
    const int wid  = tid >> 6;
    const int lane = tid & 63;
    const int l16  = lane & 15;
    const int quad = lane >> 4;
    const int wm   = (wid >> 1) * 64;
    const int wn   = (wid & 1) * 64;
    const long m0  = (long)blockIdx.x * 128;
    const long n0  = (long)blockIdx.y * 128;
    const int rsub = lane >> 3;
    const int csub = (lane & 7) * 8;

    floatx4 acc[4][4];
#pragma unroll
    for (int i = 0; i < 4; i++)
#pragma unroll
        for (int j = 0; j < 4; j++) acc[i][j] = floatx4{0.f, 0.f, 0.f, 0.f};

    for (int kt = 0; kt < K; kt += 64) {
#pragma unroll
        for (int c = 0; c < 4; ++c) {
            int chunk = wid * 4 + c;           // wave-uniform
            int row = chunk * 8 + rsub;
            long aoff = (m0 + row) * (long)K + kt + csub;
            long boff = (n0 + row) * (long)K + kt + csub;
            gload16(Ahi + aoff, (void*)(Ash + chunk * 512));
            gload16(Alo + aoff, (void*)(Asl + chunk * 512));
            gload16(Bhi + boff, (void*)(Bsh + chunk * 512));
            gload16(Blo + boff, (void*)(Bsl + chunk * 512));
        }
        __syncthreads();
#pragma unroll
        for (int ks = 0; ks < 2; ++ks) {
            bf16x8 ah[4], al[4], bh[4], bl[4];
#pragma unroll
            for (int i = 0; i < 4; i++) {
                int off = (wm + i * 16 + l16) * 64 + ks * 32 + quad * 8;
                ah[i] = *(const bf16x8*)&Ash[off];
                al[i] = *(const bf16x8*)&Asl[off];
            }
#pragma unroll
            for (int j = 0; j < 4; j++) {
                int off = (wn + j * 16 + l16) * 64 + ks * 32 + quad * 8;
                bh[j] = *(const bf16x8*)&Bsh[off];
                bl[j] = *(const bf16x8*)&Bsl[off];
            }
#pragma unroll
            for (int i = 0; i < 4; i++)
#pragma unroll
                for (int j = 0; j < 4; j++) {
                    acc[i][j] = __builtin_amdgcn_mfma_f32_16x16x32_bf16(ah[i], bh[j], acc[i][j], 0, 0, 0);
                    acc[i][j] = __builtin_amdgcn_mfma_f32_16x16x32_bf16(ah[i], bl[j], acc[i][j], 0, 0, 0);
                    acc[i][j] = __builtin_amdgcn_mfma_f32_16x16x32_bf16(al[i], bh[j], acc[i][j], 0, 0, 0);
                }
        }
        __syncthreads();
    }

#pragma unroll
    for (int i = 0; i < 4; i++) {
#pragma unroll
        for (int j = 0; j < 4; j++) {
            long row = m0 + wm + i * 16 + quad * 4;
            long col = n0 + wn + j * 16 + l16;
            float bb = bias ? bias[col] : 0.f;
#pragma unroll
            for (int r = 0; r < 4; r++) {
                float v = acc[i][j][r] + bb;
                if (DO_RELU) v = fmaxf(v, 0.f);
                long idx = (row + r) * (long)N + col;
                if (OUT_MODE == 0) {
                    ((float*)C0)[idx] = v;
                } else if (OUT_MODE == 1) {
                    ((u16*)C0)[idx] = f2bf(v);
                } else {
                    u16 hi = f2bf(v);
                    ((u16*)C0)[idx] = hi;
                    Clo[idx] = f2bf(v - bf2f(hi));
                }
            }
        }
    }
}

// ============================================================================
// Per-batch attention with split-precision scores:
// scores = (qhi+qlo)·(khi+klo)^T via 3-pass MFMA; mask; softmax.
// Writes att fp32 -> att_out, att bf16 -> att_b. Pointers are chunk-local.
// ============================================================================
__global__ __launch_bounds__(256)
void attn3(const u16* __restrict__ qhi, const u16* __restrict__ qlo,
           const u16* __restrict__ khi, const u16* __restrict__ klo,
           const float* __restrict__ mask,
           float* __restrict__ att_out, u16* __restrict__ att_b)
{
    __shared__ u16 Ash[128 * 64];
    __shared__ u16 Asl[128 * 64];
    __shared__ u16 Bsh[128 * 64];
    __shared__ u16 Bsl[128 * 64];
    __shared__ float red[2][128];
    const int b    = blockIdx.x;         // chunk-local batch
    const int tid  = threadIdx.x;
    const int wid  = tid >> 6;
    const int lane = tid & 63;
    const int l16  = lane & 15;
    const int quad = lane >> 4;
    const int wm   = (wid >> 1) * 64;
    const int wn   = (wid & 1) * 64;
    const int rsub = lane >> 3;
    const int csub = (lane & 7) * 8;

    const size_t qoff = (size_t)b * (N_SZ * KD);

    floatx4 acc[4][4];
#pragma unroll
    for (int i = 0; i < 4; i++)
#pragma unroll
        for (int j = 0; j < 4; j++) acc[i][j] = floatx4{0.f, 0.f, 0.f, 0.f};

    for (int kt = 0; kt < KD; kt += 64) {
#pragma unroll
        for (int c = 0; c < 4; ++c) {
            int chunk = wid * 4 + c;
            int row = chunk * 8 + rsub;
            size_t off = qoff + (size_t)row * KD + kt + csub;
            gload16(qhi + off, (void*)(Ash + chunk * 512));
            gload16(qlo + off, (void*)(Asl + chunk * 512));
            gload16(khi + off, (void*)(Bsh + chunk * 512));
            gload16(klo + off, (void*)(Bsl + chunk * 512));
        }
        __syncthreads();
#pragma unroll
        for (int ks = 0; ks < 2; ++ks) {
            bf16x8 ah[4], al[4], bh[4], bl[4];
#pragma unroll
            for (int i = 0; i < 4; i++) {
                int off = (wm + i * 16 + l16) * 64 + ks * 32 + quad * 8;
                ah[i] = *(const bf16x8*)&Ash[off];
                al[i] = *(const bf16x8*)&Asl[off];
            }
#pragma unroll
            for (int j = 0; j < 4; j++) {
                int off = (wn + j * 16 + l16) * 64 + ks * 32 + quad * 8;
                bh[j] = *(const bf16x8*)&Bsh[off];
                bl[j] = *(const bf16x8*)&Bsl[off];
            }
#pragma unroll
            for (int i = 0; i < 4; i++)
#pragma unroll
                for (int j = 0; j < 4; j++) {
                    acc[i][j] = __builtin_amdgcn_mfma_f32_16x16x32_bf16(ah[i], bh[j], acc[i][j], 0, 0, 0);
                    acc[i][j] = __builtin_amdgcn_mfma_f32_16x16x32_bf16(ah[i], bl[j], acc[i][j], 0, 0, 0);
                    acc[i][j] = __builtin_amdgcn_mfma_f32_16x16x32_bf16(al[i], bh[j], acc[i][j], 0, 0, 0);
                }
        }
        __syncthreads();
    }

    const float* mb = mask + (size_t)b * (N_SZ * N_SZ);

    float rmax[4][4];
#pragma unroll
    for (int i = 0; i < 4; i++) {
#pragma unroll
        for (int r = 0; r < 4; r++) {
            int row = wm + i * 16 + quad * 4 + r;
            float mx = -1e30f;
#pragma unroll
            for (int j = 0; j < 4; j++) {
                int col = wn + j * 16 + l16;
                float mval = mb[row * N_SZ + col];
                float val = acc[i][j][r] * mval - 1000.f * (1.f - mval);
                acc[i][j][r] = val;
                mx = fmaxf(mx, val);
            }
#pragma unroll
            for (int s = 1; s < 16; s <<= 1) mx = fmaxf(mx, __shfl_xor(mx, s, 64));
            rmax[i][r] = mx;
        }
    }
    if (l16 == 0) {
#pragma unroll
        for (int i = 0; i < 4; i++)
#pragma unroll
            for (int r = 0; r < 4; r++)
                red[wid & 1][wm + i * 16 + quad * 4 + r] = rmax[i][r];
    }
    __syncthreads();
#pragma unroll
    for (int i = 0; i < 4; i++)
#pragma unroll
        for (int r = 0; r < 4; r++) {
            int row = wm + i * 16 + quad * 4 + r;
            rmax[i][r] = fmaxf(red[0][row], red[1][row]);
        }
    __syncthreads();

    float rsum[4][4];
#pragma unroll
    for (int i = 0; i < 4; i++) {
#pragma unroll
        for (int r = 0; r < 4; r++) {
            float s = 0.f;
#pragma unroll
            for (int j = 0; j < 4; j++) {
                float e = __expf(acc[i][j][r] - rmax[i][r]);
                acc[i][j][r] = e;
                s += e;
            }
#pragma unroll
            for (int t = 1; t < 16; t <<= 1) s += __shfl_xor(s, t, 64);
            rsum[i][r] = s;
        }
    }
    if (l16 == 0) {
#pragma unroll
        for (int i = 0; i < 4; i++)
#pragma unroll
            for (int r = 0; r < 4; r++)
                red[wid & 1][wm + i * 16 + quad * 4 + r] = rsum[i][r];
    }
    __syncthreads();

    float* ao = att_out + (size_t)b * (N_SZ * N_SZ);
    u16*   ab = att_b   + (size_t)b * (N_SZ * N_SZ);
#pragma unroll
    for (int i = 0; i < 4; i++) {
#pragma unroll
        for (int r = 0; r < 4; r++) {
            int row = wm + i * 16 + quad * 4 + r;
            float inv = 1.f / (red[0][row] + red[1][row]);
#pragma unroll
            for (int j = 0; j < 4; j++) {
                int col = wn + j * 16 + l16;
                float a = acc[i][j][r] * inv;
                ao[row * N_SZ + col] = a;
                ab[row * N_SZ + col] = f2bf(a);
            }
        }
    }
}

// ============================================================================
// ctx[b] = att_b[b] (128x128) @ v[b] (128x256); single-pass bf16.
// ============================================================================
#define BSW 72
__global__ __launch_bounds__(256)
void ctx_gemm(const u16* __restrict__ att_b, const u16* __restrict__ v,
              u16* __restrict__ ctx)
{
    __shared__ u16 As[128 * 64];
    __shared__ u16 Bs[128 * BSW];
    const int b   = blockIdx.x;
    const int h0  = blockIdx.y * 128;
    const int tid  = threadIdx.x;
    const int wid  = tid >> 6;
    const int lane = tid & 63;
    const int l16  = lane & 15;
    const int quad = lane >> 4;
    const int wm   = (wid >> 1) * 64;
    const int wn   = (wid & 1) * 64;
    const int rsub = lane >> 3;
    const int csub = (lane & 7) * 8;

    const u16* ab = att_b + (size_t)b * (N_SZ * N_SZ);
    const u16* vb = v     + (size_t)b * (N_SZ * HID);

    floatx4 acc[4][4];
#pragma unroll
    for (int i = 0; i < 4; i++)
#pragma unroll
        for (int j = 0; j < 4; j++) acc[i][j] = floatx4{0.f, 0.f, 0.f, 0.f};

    for (int kt = 0; kt < 128; kt += 64) {
#pragma unroll
        for (int c = 0; c < 4; ++c) {
            int chunk = wid * 4 + c;
            int row = chunk * 8 + rsub;
            gload16(ab + (size_t)row * N_SZ + kt + csub, (void*)(As + chunk * 512));
        }
#pragma unroll
        for (int p = 0; p < 4; ++p) {
            int m_local = p * 16 + (tid >> 4);
            int hl8 = (tid & 15) * 8;
            u16x8 d = *(const u16x8*)(vb + (size_t)(kt + m_local) * HID + h0 + hl8);
#pragma unroll
            for (int u = 0; u < 8; ++u)
                Bs[(hl8 + u) * BSW + m_local] = d[u];
        }
        __syncthreads();
#pragma unroll
        for (int ks = 0; ks < 2; ++ks) {
            bf16x8 af[4], bfr[4];
#pragma unroll
            for (int i = 0; i < 4; i++)
                af[i] = *(const bf16x8*)&As[(wm + i * 16 + l16) * 64 + ks * 32 + quad * 8];
#pragma unroll
            for (int j = 0; j < 4; j++)
                bfr[j] = *(const bf16x8*)&Bs[(wn + j * 16 + l16) * BSW + ks * 32 + quad * 8];
#pragma unroll
            for (int i = 0; i < 4; i++)
#pragma unroll
                for (int j = 0; j < 4; j++)
                    acc[i][j] = __builtin_amdgcn_mfma_f32_16x16x32_bf16(af[i], bfr[j], acc[i][j], 0, 0, 0);
        }
        __syncthreads();
    }

#pragma unroll
    for (int i = 0; i < 4; i++) {
#pragma unroll
        for (int j = 0; j < 4; j++) {
            int row = wm + i * 16 + quad * 4;
            int col = h0 + wn + j * 16 + l16;
#pragma unroll
            for (int r = 0; r < 4; r++)
                ctx[((size_t)b * N_SZ + row + r) * HID + col] = f2bf(acc[i][j][r]);
        }
    }
}

// ============================================================================
// Single-pass gemm_bt (for the final out GEMM): C = relu(A·Bt^T + bias), fp32 out
// ============================================================================
__global__ __launch_bounds__(256)
void gemm_bt_f32(const u16* __restrict__ A, const u16* __restrict__ Bt,
                 const float* __restrict__ bias, float* __restrict__ C,
                 int M, int N, int K)
{
    __shared__ u16 As[128 * 64];
    __shared__ u16 Bs[128 * 64];
    const int tid  = threadIdx.x;
    const int wid  = tid >> 6;
    const int lane = tid & 63;
    const int l16  = lane & 15;
    const int quad = lane >> 4;
    const int wm   = (wid >> 1) * 64;
    const int wn   = (wid & 1) * 64;
    const long m0  = (long)blockIdx.x * 128;
    const long n0  = (long)blockIdx.y * 128;
    const int rsub = lane >> 3;
    const int csub = (lane & 7) * 8;

    floatx4 acc[4][4];
#pragma unroll
    for (int i = 0; i < 4; i++)
#pragma unroll
        for (int j = 0; j < 4; j++) acc[i][j] = floatx4{0.f, 0.f, 0.f, 0.f};

    for (int kt = 0; kt < K; kt += 64) {
#pragma unroll
        for (int c = 0; c < 4; ++c) {
            int chunk = wid * 4 + c;
            int row = chunk * 8 + rsub;
            gload16(A  + (m0 + row) * (long)K + kt + csub, (void*)(As + chunk * 512));
            gload16(Bt + (n0 + row) * (long)K + kt + csub, (void*)(Bs + chunk * 512));
        }
        __syncthreads();
#pragma unroll
        for (int ks = 0; ks < 2; ++ks) {
            bf16x8 af[4], bfr[4];
#pragma unroll
            for (int i = 0; i < 4; i++)
                af[i] = *(const bf16x8*)&As[(wm + i * 16 + l16) * 64 + ks * 32 + quad * 8];
#pragma unroll
            for (int j = 0; j < 4; j++)
                bfr[j] = *(const bf16x8*)&Bs[(wn + j * 16 + l16) * 64 + ks * 32 + quad * 8];
#pragma unroll
            for (int i = 0; i < 4; i++)
#pragma unroll
                for (int j = 0; j < 4; j++)
                    acc[i][j] = __builtin_amdgcn_mfma_f32_16x16x32_bf16(af[i], bfr[j], acc[i][j], 0, 0, 0);
        }
        __syncthreads();
    }

#pragma unroll
    for (int i = 0; i < 4; i++) {
#pragma unroll
        for (int j = 0; j < 4; j++) {
            long row = m0 + wm + i * 16 + quad * 4;
            long col = n0 + wn + j * 16 + l16;
            float bb = bias[col];
#pragma unroll
            for (int r = 0; r < 4; r++) {
                float v = fmaxf(acc[i][j][r] + bb, 0.f);
                C[(row + r) * (long)N + col] = v;
            }
        }
    }
}

// ============================================================================
// prep kernels
// ============================================================================
__global__ __launch_bounds__(256)
void xsplit(const float* __restrict__ x, u16* __restrict__ hi, u16* __restrict__ lo, long n)
{
    long i = ((long)blockIdx.x * blockDim.x + threadIdx.x) * 4;
    if (i < n) {
        float4 f = *(const float4*)(x + i);
        u16x4 oh, ol;
        float vv[4] = {f.x, f.y, f.z, f.w};
#pragma unroll
        for (int t = 0; t < 4; t++) {
            u16 h = f2bf(vv[t]);
            oh[t] = h;
            ol[t] = f2bf(vv[t] - bf2f(h));
        }
        *(u16x4*)(hi + i) = oh;
        *(u16x4*)(lo + i) = ol;
    }
}

__global__ __launch_bounds__(256)
void wsplit_trans(const float* __restrict__ W, u16* __restrict__ Whi, u16* __restrict__ Wlo,
                  int K, int Nc)
{
    int idx = blockIdx.x * 256 + threadIdx.x;
    if (idx < K * Nc) {
        int k = idx / Nc, n = idx % Nc;
        float v = W[idx];
        u16 h = f2bf(v);
        Whi[(size_t)n * K + k] = h;
        Wlo[(size_t)n * K + k] = f2bf(v - bf2f(h));
    }
}

// ============================================================================
extern "C" void kernel_launch(void* const* d_in, const int* in_sizes, int n_in,
                              void* d_out, int out_size, void* d_ws, size_t ws_size,
                              hipStream_t stream)
{
    const float* x    = (const float*)d_in[0];
    const float* mask = (const float*)d_in[1];
    const float* Wv   = (const float*)d_in[2];
    const float* bv   = (const float*)d_in[3];
    const float* Wq   = (const float*)d_in[4];
    const float* bq   = (const float*)d_in[5];
    const float* Wk   = (const float*)d_in[6];
    const float* bk   = (const float*)d_in[7];
    const float* Wo   = (const float*)d_in[8];
    const float* bo   = (const float*)d_in[9];

    float* out = (float*)d_out;                          // [B,N,DOUT]
    float* att = out + (size_t)B_SZ * N_SZ * DOUT;       // [B,N,N]

    const size_t M = (size_t)B_SZ * N_SZ;

    // ---- workspace layout (bytes) ----
    char* ws = (char*)d_ws;
    size_t o = 0;
    u16* xhi = (u16*)(ws + o); o += M * DIN * 2;                  // 67,108,864
    u16* xlo = (u16*)(ws + o); o += M * DIN * 2;                  // 67,108,864
    u16* Wq_h = (u16*)(ws + o); o += (size_t)KD * DIN * 2;
    u16* Wq_l = (u16*)(ws + o); o += (size_t)KD * DIN * 2;
    u16* Wk_h = (u16*)(ws + o); o += (size_t)KD * DIN * 2;
    u16* Wk_l = (u16*)(ws + o); o += (size_t)KD * DIN * 2;
    u16* Wv_h = (u16*)(ws + o); o += (size_t)HID * DIN * 2;
    u16* Wv_l = (u16*)(ws + o); o += (size_t)HID * DIN * 2;
    u16* Wo_h = (u16*)(ws + o); o += (size_t)DOUT * HID * 2;
    u16* Wo_l = (u16*)(ws + o); o += (size_t)DOUT * HID * 2;
    u16* qhi = (u16*)(ws + o); o += (size_t)MC * KD * 2;          // 33.5 MB each
    u16* qlo = (u16*)(ws + o); o += (size_t)MC * KD * 2;
    u16* khi = (u16*)(ws + o); o += (size_t)MC * KD * 2;
    u16* klo = (u16*)(ws + o); o += (size_t)MC * KD * 2;
    u16* vbuf = (u16*)(ws + o); o += (size_t)MC * HID * 2;        // 16.8 MB
    u16* attb = (u16*)(ws + o); o += (size_t)BC * N_SZ * N_SZ * 2;// 8.4 MB
    u16* ctx  = (u16*)(ws + o); o += (size_t)MC * HID * 2;        // 16.8 MB
    // total ~315 MB

    // 1) x -> hi/lo bf16 planes
    xsplit<<<(unsigned)(M * DIN / 4 / 256), 256, 0, stream>>>(x, xhi, xlo, (long)M * DIN);

    // 2) weights -> hi/lo bf16, transposed [n][k]
    wsplit_trans<<<(DIN * KD + 255) / 256, 256, 0, stream>>>(Wq, Wq_h, Wq_l, DIN, KD);
    wsplit_trans<<<(DIN * KD + 255) / 256, 256, 0, stream>>>(Wk, Wk_h, Wk_l, DIN, KD);
    wsplit_trans<<<(DIN * HID + 255) / 256, 256, 0, stream>>>(Wv, Wv_h, Wv_l, DIN, HID);
    wsplit_trans<<<(HID * DOUT + 255) / 256, 256, 0, stream>>>(Wo, Wo_h, Wo_l, HID, DOUT);

    for (int c = 0; c < NCHUNK; ++c) {
        const u16* xh_c = xhi + (size_t)c * MC * DIN;
        const u16* xl_c = xlo + (size_t)c * MC * DIN;
        const float* mask_c = mask + (size_t)c * BC * N_SZ * N_SZ;
        float* att_c = att + (size_t)c * BC * N_SZ * N_SZ;
        float* out_c = out + (size_t)c * MC * DOUT;

        // 3) projections (split 3-pass): q,k -> hi/lo planes; v -> single bf16
        gemm3<1, 2><<<dim3(MC / 128, KD / 128), 256, 0, stream>>>(
            xh_c, xl_c, Wq_h, Wq_l, bq, qhi, qlo, MC, KD, DIN);
        gemm3<1, 2><<<dim3(MC / 128, KD / 128), 256, 0, stream>>>(
            xh_c, xl_c, Wk_h, Wk_l, bk, khi, klo, MC, KD, DIN);
        gemm3<1, 1><<<dim3(MC / 128, HID / 128), 256, 0, stream>>>(
            xh_c, xl_c, Wv_h, Wv_l, bv, vbuf, nullptr, MC, HID, DIN);

        // 4) scores (split 3-pass) + mask + softmax
        attn3<<<BC, 256, 0, stream>>>(qhi, qlo, khi, klo, mask_c, att_c, attb);

        // 5) ctx = att @ v
        ctx_gemm<<<dim3(BC, HID / 128), 256, 0, stream>>>(attb, vbuf, ctx);

        // 6) out = relu(ctx @ Wo + bo)
        gemm_bt_f32<<<dim3(MC / 128, DOUT / 128), 256, 0, stream>>>(
            ctx, Wo_h, bo, out_c, MC, DOUT, HID);
    }

    (void)in_sizes; (void)n_in; (void)out_size; (void)ws_size;
}

// Round 3
// 717.400 us; speedup vs baseline: 1.3838x; 1.3838x over previous
//
#include <hip/hip_runtime.h>
#include <cstdint>
#include <cstddef>

// ---- problem dims (fixed) ----
#define B_SZ 1024
#define N_SZ 128
#define DIN 256
#define HID 256
#define DOUT 256
#define KD 512   // 4*N

typedef unsigned short u16;
typedef _Float16 f16x8 __attribute__((ext_vector_type(8)));
typedef float floatx4 __attribute__((ext_vector_type(4)));
typedef unsigned short u16x8 __attribute__((ext_vector_type(8)));
typedef unsigned short u16x4 __attribute__((ext_vector_type(4)));

__device__ __forceinline__ u16 f2h(float f) {
    _Float16 h = (_Float16)f;           // RNE
    return *(u16*)&h;
}

__device__ __forceinline__ void gload16(const void* g, void* lds) {
    // async global->LDS, 16B per lane; LDS dest = wave-uniform base + lane*16
    __builtin_amdgcn_global_load_lds(
        (__attribute__((address_space(1))) void*)const_cast<void*>(g),
        (__attribute__((address_space(3))) void*)lds,
        16, 0, 0);
}

// ============================================================================
// gemm_bt (fp16 single-pass): C[m][n] = act( sum_k A[m][k]*Bt[n][k] + bias[n] )
// A: [M][K] fp16 row-major, Bt: [N][K] fp16 row-major.
// 128x128 tile, BK=64, 256 threads = 4 waves 2x2. OUT_F32: fp32 else fp16 out.
// ============================================================================
template<int OUT_F32>
__global__ __launch_bounds__(256)
void gemm_bt(const u16* __restrict__ A, const u16* __restrict__ Bt,
             const float* __restrict__ bias, void* __restrict__ C,
             int M, int N, int K)
{
    __shared__ u16 As[128 * 64];
    __shared__ u16 Bs[128 * 64];
    const int tid  = threadIdx.x;
    const int wid  = tid >> 6;
    const int lane = tid & 63;
    const int l16  = lane & 15;
    const int quad = lane >> 4;
    const int wm   = (wid >> 1) * 64;
    const int wn   = (wid & 1) * 64;
    const long m0  = (long)blockIdx.x * 128;
    const long n0  = (long)blockIdx.y * 128;
    const int rsub = lane >> 3;        // 0..7
    const int csub = (lane & 7) * 8;   // 0..56

    floatx4 acc[4][4];
#pragma unroll
    for (int i = 0; i < 4; i++)
#pragma unroll
        for (int j = 0; j < 4; j++) acc[i][j] = floatx4{0.f, 0.f, 0.f, 0.f};

    for (int kt = 0; kt < K; kt += 64) {
#pragma unroll
        for (int c = 0; c < 4; ++c) {
            int chunk = wid * 4 + c;           // wave-uniform
            int row = chunk * 8 + rsub;
            gload16(A  + (m0 + row) * (long)K + kt + csub, (void*)(As + chunk * 512));
            gload16(Bt + (n0 + row) * (long)K + kt + csub, (void*)(Bs + chunk * 512));
        }
        __syncthreads();
#pragma unroll
        for (int ks = 0; ks < 2; ++ks) {
            f16x8 af[4], bfr[4];
#pragma unroll
            for (int i = 0; i < 4; i++)
                af[i] = *(const f16x8*)&As[(wm + i * 16 + l16) * 64 + ks * 32 + quad * 8];
#pragma unroll
            for (int j = 0; j < 4; j++)
                bfr[j] = *(const f16x8*)&Bs[(wn + j * 16 + l16) * 64 + ks * 32 + quad * 8];
#pragma unroll
            for (int i = 0; i < 4; i++)
#pragma unroll
                for (int j = 0; j < 4; j++)
                    acc[i][j] = __builtin_amdgcn_mfma_f32_16x16x32_f16(af[i], bfr[j], acc[i][j], 0, 0, 0);
        }
        __syncthreads();
    }

#pragma unroll
    for (int i = 0; i < 4; i++) {
#pragma unroll
        for (int j = 0; j < 4; j++) {
            long row = m0 + wm + i * 16 + quad * 4;  // C layout: row=quad*4+r, col=l16
            long col = n0 + wn + j * 16 + l16;
            float bb = bias[col];
#pragma unroll
            for (int r = 0; r < 4; r++) {
                float v = fmaxf(acc[i][j][r] + bb, 0.f);   // relu
                long idx = (row + r) * (long)N + col;
                if (OUT_F32) ((float*)C)[idx] = v;
                else         ((u16*)C)[idx] = f2h(v);
            }
        }
    }
}

// ============================================================================
// Per-batch attention: scores = q_b . k_b^T (K=512) fp16 single-pass,
// mask, softmax. Writes att fp32 -> d_out region + att fp16 -> ws.
// ============================================================================
__global__ __launch_bounds__(256)
void attn_softmax(const u16* __restrict__ q, const u16* __restrict__ kk,
                  const float* __restrict__ mask,
                  float* __restrict__ att_out, u16* __restrict__ att_h)
{
    __shared__ u16 As[128 * 64];
    __shared__ u16 Bs[128 * 64];
    __shared__ float red[2][128];
    const int b    = blockIdx.x;
    const int tid  = threadIdx.x;
    const int wid  = tid >> 6;
    const int lane = tid & 63;
    const int l16  = lane & 15;
    const int quad = lane >> 4;
    const int wm   = (wid >> 1) * 64;
    const int wn   = (wid & 1) * 64;
    const int rsub = lane >> 3;
    const int csub = (lane & 7) * 8;

    const u16* qb = q  + (size_t)b * (N_SZ * KD);
    const u16* kb = kk + (size_t)b * (N_SZ * KD);

    floatx4 acc[4][4];
#pragma unroll
    for (int i = 0; i < 4; i++)
#pragma unroll
        for (int j = 0; j < 4; j++) acc[i][j] = floatx4{0.f, 0.f, 0.f, 0.f};

    for (int kt = 0; kt < KD; kt += 64) {
#pragma unroll
        for (int c = 0; c < 4; ++c) {
            int chunk = wid * 4 + c;
            int row = chunk * 8 + rsub;
            gload16(qb + (size_t)row * KD + kt + csub, (void*)(As + chunk * 512));
            gload16(kb + (size_t)row * KD + kt + csub, (void*)(Bs + chunk * 512));
        }
        __syncthreads();
#pragma unroll
        for (int ks = 0; ks < 2; ++ks) {
            f16x8 af[4], bfr[4];
#pragma unroll
            for (int i = 0; i < 4; i++)
                af[i] = *(const f16x8*)&As[(wm + i * 16 + l16) * 64 + ks * 32 + quad * 8];
#pragma unroll
            for (int j = 0; j < 4; j++)
                bfr[j] = *(const f16x8*)&Bs[(wn + j * 16 + l16) * 64 + ks * 32 + quad * 8];
#pragma unroll
            for (int i = 0; i < 4; i++)
#pragma unroll
                for (int j = 0; j < 4; j++)
                    acc[i][j] = __builtin_amdgcn_mfma_f32_16x16x32_f16(af[i], bfr[j], acc[i][j], 0, 0, 0);
        }
        __syncthreads();
    }

    const float* mb = mask + (size_t)b * (N_SZ * N_SZ);

    // mask + row max (C layout: row=quad*4+r, col=l16 within 16-lane group)
    float rmax[4][4];
#pragma unroll
    for (int i = 0; i < 4; i++) {
#pragma unroll
        for (int r = 0; r < 4; r++) {
            int row = wm + i * 16 + quad * 4 + r;
            float mx = -1e30f;
#pragma unroll
            for (int j = 0; j < 4; j++) {
                int col = wn + j * 16 + l16;
                float mval = mb[row * N_SZ + col];
                float val = acc[i][j][r] * mval - 1000.f * (1.f - mval);
                acc[i][j][r] = val;
                mx = fmaxf(mx, val);
            }
#pragma unroll
            for (int s = 1; s < 16; s <<= 1) mx = fmaxf(mx, __shfl_xor(mx, s, 64));
            rmax[i][r] = mx;
        }
    }
    if (l16 == 0) {
#pragma unroll
        for (int i = 0; i < 4; i++)
#pragma unroll
            for (int r = 0; r < 4; r++)
                red[wid & 1][wm + i * 16 + quad * 4 + r] = rmax[i][r];
    }
    __syncthreads();
#pragma unroll
    for (int i = 0; i < 4; i++)
#pragma unroll
        for (int r = 0; r < 4; r++) {
            int row = wm + i * 16 + quad * 4 + r;
            rmax[i][r] = fmaxf(red[0][row], red[1][row]);
        }
    __syncthreads();

    float rsum[4][4];
#pragma unroll
    for (int i = 0; i < 4; i++) {
#pragma unroll
        for (int r = 0; r < 4; r++) {
            float s = 0.f;
#pragma unroll
            for (int j = 0; j < 4; j++) {
                float e = __expf(acc[i][j][r] - rmax[i][r]);
                acc[i][j][r] = e;
                s += e;
            }
#pragma unroll
            for (int t = 1; t < 16; t <<= 1) s += __shfl_xor(s, t, 64);
            rsum[i][r] = s;
        }
    }
    if (l16 == 0) {
#pragma unroll
        for (int i = 0; i < 4; i++)
#pragma unroll
            for (int r = 0; r < 4; r++)
                red[wid & 1][wm + i * 16 + quad * 4 + r] = rsum[i][r];
    }
    __syncthreads();

    float* ao = att_out + (size_t)b * (N_SZ * N_SZ);
    u16*   ah = att_h   + (size_t)b * (N_SZ * N_SZ);
#pragma unroll
    for (int i = 0; i < 4; i++) {
#pragma unroll
        for (int r = 0; r < 4; r++) {
            int row = wm + i * 16 + quad * 4 + r;
            float inv = 1.f / (red[0][row] + red[1][row]);   // >= 1, safe
#pragma unroll
            for (int j = 0; j < 4; j++) {
                int col = wn + j * 16 + l16;
                float a = acc[i][j][r] * inv;
                ao[row * N_SZ + col] = a;
                ah[row * N_SZ + col] = f2h(a);
            }
        }
    }
}

// ============================================================================
// ctx[b] = att[b] (128x128) @ v[b] (128x256); v transposed during LDS staging.
// grid (B, 2): blockIdx.y selects 128-wide h tile. fp16 out.
// ============================================================================
#define BSW 72   // padded Bs row stride (16B-aligned)
__global__ __launch_bounds__(256)
void ctx_gemm(const u16* __restrict__ att_h, const u16* __restrict__ v,
              u16* __restrict__ ctx)
{
    __shared__ u16 As[128 * 64];
    __shared__ u16 Bs[128 * BSW];
    const int b   = blockIdx.x;
    const int h0  = blockIdx.y * 128;
    const int tid  = threadIdx.x;
    const int wid  = tid >> 6;
    const int lane = tid & 63;
    const int l16  = lane & 15;
    const int quad = lane >> 4;
    const int wm   = (wid >> 1) * 64;
    const int wn   = (wid & 1) * 64;
    const int rsub = lane >> 3;
    const int csub = (lane & 7) * 8;

    const u16* ab = att_h + (size_t)b * (N_SZ * N_SZ);
    const u16* vb = v     + (size_t)b * (N_SZ * HID);

    floatx4 acc[4][4];
#pragma unroll
    for (int i = 0; i < 4; i++)
#pragma unroll
        for (int j = 0; j < 4; j++) acc[i][j] = floatx4{0.f, 0.f, 0.f, 0.f};

    for (int kt = 0; kt < 128; kt += 64) {
#pragma unroll
        for (int c = 0; c < 4; ++c) {
            int chunk = wid * 4 + c;
            int row = chunk * 8 + rsub;
            gload16(ab + (size_t)row * N_SZ + kt + csub, (void*)(As + chunk * 512));
        }
        // stage v[m][h] -> Bs[h_local][m_local]  (transpose in LDS)
#pragma unroll
        for (int p = 0; p < 4; ++p) {
            int m_local = p * 16 + (tid >> 4);
            int hl8 = (tid & 15) * 8;
            u16x8 d = *(const u16x8*)(vb + (size_t)(kt + m_local) * HID + h0 + hl8);
#pragma unroll
            for (int u = 0; u < 8; ++u)
                Bs[(hl8 + u) * BSW + m_local] = d[u];
        }
        __syncthreads();
#pragma unroll
        for (int ks = 0; ks < 2; ++ks) {
            f16x8 af[4], bfr[4];
#pragma unroll
            for (int i = 0; i < 4; i++)
                af[i] = *(const f16x8*)&As[(wm + i * 16 + l16) * 64 + ks * 32 + quad * 8];
#pragma unroll
            for (int j = 0; j < 4; j++)
                bfr[j] = *(const f16x8*)&Bs[(wn + j * 16 + l16) * BSW + ks * 32 + quad * 8];
#pragma unroll
            for (int i = 0; i < 4; i++)
#pragma unroll
                for (int j = 0; j < 4; j++)
                    acc[i][j] = __builtin_amdgcn_mfma_f32_16x16x32_f16(af[i], bfr[j], acc[i][j], 0, 0, 0);
        }
        __syncthreads();
    }

#pragma unroll
    for (int i = 0; i < 4; i++) {
#pragma unroll
        for (int j = 0; j < 4; j++) {
            int row = wm + i * 16 + quad * 4;
            int col = h0 + wn + j * 16 + l16;
#pragma unroll
            for (int r = 0; r < 4; r++)
                ctx[((size_t)b * N_SZ + row + r) * HID + col] = f2h(acc[i][j][r]);
        }
    }
}

// ============================================================================
// prep kernels
// ============================================================================
__global__ __launch_bounds__(256)
void xcvt(const float* __restrict__ x, u16* __restrict__ y, long n)
{
    long i = ((long)blockIdx.x * blockDim.x + threadIdx.x) * 8;
    if (i < n) {
        float4 f0 = *(const float4*)(x + i);
        float4 f1 = *(const float4*)(x + i + 4);
        u16x8 o;
        o[0] = f2h(f0.x); o[1] = f2h(f0.y); o[2] = f2h(f0.z); o[3] = f2h(f0.w);
        o[4] = f2h(f1.x); o[5] = f2h(f1.y); o[6] = f2h(f1.z); o[7] = f2h(f1.w);
        *(u16x8*)(y + i) = o;
    }
}

__global__ __launch_bounds__(256)
void wtrans(const float* __restrict__ W, u16* __restrict__ Wt, int K, int Nc)
{
    int idx = blockIdx.x * 256 + threadIdx.x;
    if (idx < K * Nc) {
        int k = idx / Nc, n = idx % Nc;
        Wt[(size_t)n * K + k] = f2h(W[idx]);
    }
}

// ============================================================================
extern "C" void kernel_launch(void* const* d_in, const int* in_sizes, int n_in,
                              void* d_out, int out_size, void* d_ws, size_t ws_size,
                              hipStream_t stream)
{
    const float* x    = (const float*)d_in[0];
    const float* mask = (const float*)d_in[1];
    const float* Wv   = (const float*)d_in[2];
    const float* bv   = (const float*)d_in[3];
    const float* Wq   = (const float*)d_in[4];
    const float* bq   = (const float*)d_in[5];
    const float* Wk   = (const float*)d_in[6];
    const float* bk   = (const float*)d_in[7];
    const float* Wo   = (const float*)d_in[8];
    const float* bo   = (const float*)d_in[9];

    float* out = (float*)d_out;                          // [B,N,DOUT]
    float* att = out + (size_t)B_SZ * N_SZ * DOUT;       // [B,N,N]

    const size_t M = (size_t)B_SZ * N_SZ;                // 131072

    // ---- workspace layout (fp16 planes, all 16B aligned) ----
    char* ws = (char*)d_ws;
    size_t o = 0;
    u16* xh   = (u16*)(ws + o); o += M * DIN * 2;                 // 67.1 MB
    u16* Wq_t = (u16*)(ws + o); o += (size_t)KD * DIN * 2;
    u16* Wk_t = (u16*)(ws + o); o += (size_t)KD * DIN * 2;
    u16* Wv_t = (u16*)(ws + o); o += (size_t)HID * DIN * 2;
    u16* Wo_t = (u16*)(ws + o); o += (size_t)DOUT * HID * 2;
    u16* qb   = (u16*)(ws + o); o += M * KD * 2;                  // 134.2 MB
    u16* kb   = (u16*)(ws + o); o += M * KD * 2;                  // 134.2 MB
    u16* vb   = (u16*)(ws + o); o += M * HID * 2;                 // 67.1 MB
    u16* attb = (u16*)(ws + o); o += (size_t)B_SZ * N_SZ * N_SZ * 2; // 33.5 MB
    u16* ctx  = xh;   // alias: xh dead after projections          -> total ~437 MB

    // 1) x -> fp16
    xcvt<<<(unsigned)(M * DIN / 8 / 256), 256, 0, stream>>>(x, xh, (long)M * DIN);

    // 2) weights -> fp16 transposed [n][k]
    wtrans<<<(DIN * KD + 255) / 256, 256, 0, stream>>>(Wq, Wq_t, DIN, KD);
    wtrans<<<(DIN * KD + 255) / 256, 256, 0, stream>>>(Wk, Wk_t, DIN, KD);
    wtrans<<<(DIN * HID + 255) / 256, 256, 0, stream>>>(Wv, Wv_t, DIN, HID);
    wtrans<<<(HID * DOUT + 255) / 256, 256, 0, stream>>>(Wo, Wo_t, HID, DOUT);

    // 3) projections: q,k,v = relu(x@W + b), fp16 out
    gemm_bt<0><<<dim3((unsigned)(M / 128), KD / 128), 256, 0, stream>>>(xh, Wq_t, bq, qb, (int)M, KD, DIN);
    gemm_bt<0><<<dim3((unsigned)(M / 128), KD / 128), 256, 0, stream>>>(xh, Wk_t, bk, kb, (int)M, KD, DIN);
    gemm_bt<0><<<dim3((unsigned)(M / 128), HID / 128), 256, 0, stream>>>(xh, Wv_t, bv, vb, (int)M, HID, DIN);

    // 4) scores + mask + softmax -> att fp32 (d_out) + att fp16 (ws)
    attn_softmax<<<B_SZ, 256, 0, stream>>>(qb, kb, mask, att, attb);

    // 5) ctx = att @ v  (fp16, aliases xh)
    ctx_gemm<<<dim3(B_SZ, HID / 128), 256, 0, stream>>>(attb, vb, ctx);

    // 6) out = relu(ctx @ Wo + bo) -> fp32 d_out
    gemm_bt<1><<<dim3((unsigned)(M / 128), DOUT / 128), 256, 0, stream>>>(ctx, Wo_t, bo, out, (int)M, DOUT, HID);

    (void)in_sizes; (void)n_in; (void)out_size; (void)ws_size;
}